// Round 3
// baseline (139.793 us; speedup 1.0000x reference)
//
#include <hip/hip_runtime.h>
#include <cstdint>
#include <cstddef>

// Problem constants (from reference)
#define B_    2
#define A_    3
#define NCLS_ 3
#define CH_   9      // N_CLS * A
#define D_    64
#define H_    128
#define W_    128
#define M_    128
#define TD    8      // d-planes per block tile
#define THT   16     // h-rows per block tile
#define EPS_      1e-4f
#define ONE_M_EPS 0.9999f
#define NLOG2E    -1.4426950408889634f   // -log2(e)
#define LN2_      0.6931471805599453f

__device__ __forceinline__ float4 fmax4(float4 a, float4 b) {
    return make_float4(fmaxf(a.x, b.x), fmaxf(a.y, b.y),
                       fmaxf(a.z, b.z), fmaxf(a.w, b.w));
}

// gfx950: __builtin_amdgcn_exp2f = v_exp_f32 (2^x), __builtin_amdgcn_logf =
// v_log_f32 (log2 x) — per __clang_hip_math.h.
__device__ __forceinline__ float exp2_fast(float x) { return __builtin_amdgcn_exp2f(x); }
__device__ __forceinline__ float log2_fast(float x) { return __builtin_amdgcn_logf(x); }

// ---------------------------------------------------------------------------
// Negative-term kernel — 2-rows-per-thread d-loop register ring (R12).
// R11 post-mortem: removing the d+-1 load redundancy recovered R9 (~40 us)
// but no more. FETCH 54 MB (~9 us at BW) + VALU ~4 us << 40 us measured =>
// latency/MLP-bound: only ~96 B/lane in flight at ~200-400 cyc L2/L3 latency.
// Fix: each thread owns TWO h-rows (R0=2*hwi, R1=R0+1); per plane-iter it
// issues 5 independent float4 loads (2 center + 1 halo + 2 pg) for 2 output
// rows -> loads/row 3->2.5 AND in-flight bytes/lane 96->160 (+67% MLP) at the
// same 2-iteration issue-to-consume distance. No barriers, no LDS staging.
// h-neighbors: inner neighbor via partner half-wave __shfl(lane^32) (even hwi
// takes partner row0 = R0+2; odd takes partner row1 = R0-1); outer neighbor
// is the single halo load (replicate-clamped at H borders). d replicate-clamp
// via ring + clamped plane loads. w via -inf lane-shuffle selects.
// Exact float max => (pooled == logits) matches the reference bit-exact.
// Swizzle: 1152 = 8 XCD x 144 chunk (bijective); within a chunk htile
// fastest, then cls (the 3 cls channels share one prob plane -> same XCD L2),
// then dchunk (d-halo neighbors same XCD), then (b,a).
// ---------------------------------------------------------------------------
struct Raw { float4 c0, c1, e, p0, p1; };

__global__ __launch_bounds__(256) void neg_kernel(
    const float* __restrict__ logits, const float* __restrict__ prob,
    float* __restrict__ partials)
{
    const int orig = blockIdx.x;
    const int swz  = (orig & 7) * 144 + (orig >> 3);   // chunked XCD swizzle
    const int tid  = threadIdx.x;
    const int lw   = tid & 31;            // w-segment index
    const int lane = tid & 63;
    const int hwi  = tid >> 5;            // 0..7: row-pair within tile
    const bool evenh = (hwi & 1) == 0;    // even hwi = lower half of wave
    const float NEG = -INFINITY;

    // decode: htile fastest, then cls, then dchunk, then g=(b,a)
    const int htile  = swz & 7;
    const int u      = swz >> 3;
    const int cls    = u % 3;
    const int v      = u / 3;
    const int dchunk = v & 7;
    const int g      = v >> 3;            // 0..5
    const int b = g / 3, a = g - 3 * b;
    const int bc = b * CH_ + cls * A_ + a;   // channel c = cls*A + a
    const int d0 = dchunk * TD;
    const int R0 = htile * THT + 2 * hwi;    // this thread's rows: R0, R0+1
    // outer halo row: even hwi needs R0-1, odd hwi needs R0+2 (clamped)
    const int er = evenh ? max(R0 - 1, 0) : min(R0 + 2, H_ - 1);

    const size_t HW = (size_t)H_ * W_;
    const float* Lc = logits + (size_t)bc * D_ * HW + 4 * lw;
    const float* Pp = prob + (size_t)(b * A_ + a) * D_ * HW + 4 * lw;
    const float* C0 = Lc + (size_t)R0 * W_;
    const float* C1 = Lc + (size_t)(R0 + 1) * W_;
    const float* Eb = Lc + (size_t)er * W_;
    const float* P0 = Pp + (size_t)R0 * W_;
    const float* P1 = Pp + (size_t)(R0 + 1) * W_;

    auto ld = [&](const float* base, int dq) -> float4 {
        const int dc = min(max(dq, 0), D_ - 1);   // d replicate-clamp
        return *(const float4*)(base + (size_t)dc * HW);
    };
    auto ldraw = [&](int dq) -> Raw {
        Raw r;
        r.c0 = ld(C0, dq); r.c1 = ld(C1, dq); r.e = ld(Eb, dq);
        r.p0 = ld(P0, dq); r.p1 = ld(P1, dq);
        return r;
    };
    // partner half-wave exchange (same w segment, other hwi of the wave)
    auto shfl4 = [&](float4 vv) -> float4 {
        const int p = lane ^ 32;
        return make_float4(__shfl(vv.x, p, 64), __shfl(vv.y, p, 64),
                           __shfl(vv.z, p, 64), __shfl(vv.w, p, 64));
    };
    // vertical (h) 3-row max for both owned rows of one plane
    auto hv = [&](const Raw& rw, float4& vm0, float4& vm1) {
        const float4 s0 = shfl4(rw.c0);   // even: partner row0 = R0+2
        const float4 s1 = shfl4(rw.c1);   // odd:  partner row1 = R0-1
        const float4 nlo = evenh ? rw.e : s1;    // row R0-1
        const float4 nhi = evenh ? s0 : rw.e;    // row R1+1
        const float4 cc = fmax4(rw.c0, rw.c1);
        vm0 = fmax4(nlo, cc);
        vm1 = fmax4(cc, nhi);
    };
    // horizontal (w) 3-max with -inf borders
    auto wmax = [&](float4 cm) -> float4 {
        const float lftv = __shfl(cm.w, (lane + 63) & 63, 64);
        const float rgtv = __shfl(cm.x, (lane + 1) & 63, 64);
        const float left  = (lw == 0)  ? NEG : lftv;
        const float right = (lw == 31) ? NEG : rgtv;
        float4 m;
        m.x = fmaxf(left, fmaxf(cm.x, cm.y));
        m.y = fmaxf(cm.x, fmaxf(cm.y, cm.z));
        m.z = fmaxf(cm.y, fmaxf(cm.z, cm.w));
        m.w = fmaxf(cm.z, fmaxf(cm.w, right));
        return m;
    };

    float lacc2 = 0.0f, cacc = 0.0f;   // lacc2 accumulates log2 units
    auto epi = [&](float x, float pgv, float mv) {
        const bool pre = (pgv == -1.0f) & (mv == x);
        if (__any(pre)) {
            const float uu = exp2_fast(x * NLOG2E);            // e^-x
            const float p = __builtin_amdgcn_fmed3f(
                                __builtin_amdgcn_rcpf(1.0f + uu), EPS_, ONE_M_EPS);
            const float wn = (pre & (p > EPS_)) ? p * p : 0.0f;
            cacc += wn;
            lacc2 = fmaf(log2_fast(1.0f - p), wn, lacc2);
        }
    };

    // ---- prologue: planes d0-1 .. d0+2 in flight ----
    const float4 am1c0 = ld(C0, d0 - 1);
    const float4 am1c1 = ld(C1, d0 - 1);
    const float4 am1e  = ld(Eb, d0 - 1);
    Raw r0   = ldraw(d0);
    Raw rawD = ldraw(d0 + 1);
    Raw rawE = ldraw(d0 + 2);

    float4 vmA0, vmA1, vmB0, vmB1;
    {
        Raw rm1; rm1.c0 = am1c0; rm1.c1 = am1c1; rm1.e = am1e;
        hv(rm1, vmA0, vmA1);
    }
    hv(r0, vmB0, vmB1);
    float4 xc0 = r0.c0, xc1 = r0.c1, pgc0 = r0.p0, pgc1 = r0.p1;

    #pragma unroll
    for (int j = 0; j < TD; ++j) {
        // issue plane d0+j+3 (deepest) before touching anything in flight
        Raw rawN;
        if (j <= TD - 3) rawN = ldraw(d0 + j + 3);
        else             rawN = rawE;      // never combined; keeps defined

        // combine plane d0+j+1 (issued 2 iterations ago)
        float4 vmC0, vmC1;
        hv(rawD, vmC0, vmC1);
        const float4 xN0 = rawD.c0, xN1 = rawD.c1;
        const float4 pN0 = rawD.p0, pN1 = rawD.p1;

        // d-direction max + w-direction max for output plane d0+j
        const float4 m0 = wmax(fmax4(vmA0, fmax4(vmB0, vmC0)));
        const float4 m1 = wmax(fmax4(vmA1, fmax4(vmB1, vmC1)));

        // epilogue: cheap pre-condition; wave-uniform skip of transcendentals
        epi(xc0.x, pgc0.x, m0.x); epi(xc0.y, pgc0.y, m0.y);
        epi(xc0.z, pgc0.z, m0.z); epi(xc0.w, pgc0.w, m0.w);
        epi(xc1.x, pgc1.x, m1.x); epi(xc1.y, pgc1.y, m1.y);
        epi(xc1.z, pgc1.z, m1.z); epi(xc1.w, pgc1.w, m1.w);

        // rotate rings
        vmA0 = vmB0; vmA1 = vmB1; vmB0 = vmC0; vmB1 = vmC1;
        xc0 = xN0; xc1 = xN1; pgc0 = pN0; pgc1 = pN1;
        rawD = rawE; rawE = rawN;
    }

    float lacc = lacc2 * (-LN2_);      // convert log2 -> -ln

    // block reduction: wave shuffle then cross-wave via LDS
    #pragma unroll
    for (int off = 32; off > 0; off >>= 1) {
        lacc += __shfl_down(lacc, off);
        cacc += __shfl_down(cacc, off);
    }
    __shared__ float rl[4], rc[4];
    const int wv = threadIdx.x >> 6;
    if (lane == 0) { rl[wv] = lacc; rc[wv] = cacc; }
    __syncthreads();
    if (threadIdx.x == 0) {
        partials[2 * (size_t)blockIdx.x]     = rl[0] + rl[1] + rl[2] + rl[3];
        partials[2 * (size_t)blockIdx.x + 1] = rc[0] + rc[1] + rc[2] + rc[3];
    }
}

// ---------------------------------------------------------------------------
// Fused positive/other terms + final reduction (single block).
// Output order: [sum l_pos, loss_neg, sum l_oth, sum c_pos, count_neg, sum c_oth]
// ---------------------------------------------------------------------------
__global__ __launch_bounds__(256) void pos_reduce_kernel(
    const float* __restrict__ logits, const float* __restrict__ prob,
    const int* __restrict__ coord, const float* __restrict__ wcls,
    const float* __restrict__ partials, int nb, float* __restrict__ out)
{
    const int tid = threadIdx.x;
    const int b = tid >> 7;               // 0 or 1
    const int m = tid & (M_ - 1);
    __shared__ int zr[B_][NCLS_];
    if (tid < B_ * NCLS_) zr[tid / NCLS_][tid % NCLS_] = 0;
    __syncthreads();

    const int* cg = coord + ((size_t)b * M_ + m) * 4;
    const int c0 = cg[0];
    const bool valid = c0 > -1;
    const int a = valid ? c0    : 0;
    const int d = valid ? cg[1] : 0;
    const int h = valid ? cg[2] : 0;
    const int w = valid ? cg[3] : 0;

    const size_t HW = (size_t)H_ * W_;
    const size_t sp = (size_t)d * HW + (size_t)h * W_ + w;

    const float pv = prob[((size_t)b * A_ + a) * D_ * HW + sp];
    const int cls = valid ? ((int)pv - 1) : 0;
    if (valid) zr[b][cls] = 1;            // zero_rows flags (benign race)
    __syncthreads();

    auto sigclip = [](float x) {
        float p = 1.0f / (1.0f + __expf(-x));
        return fminf(fmaxf(p, EPS_), ONE_M_EPS);
    };

    const float vf = valid ? 1.0f : 0.0f;
    const float pt = sigclip(logits[((size_t)(b * CH_ + cls * A_ + a)) * D_ * HW + sp]);
    const float wp = (1.0f - pt) * (1.0f - pt) * wcls[cls] * vf;
    float lpos = -__logf(pt) * wp;
    float cpos = wp;

    float loth = 0.0f, coth = 0.0f;
    const bool ptg = pt > 0.5f;
    #pragma unroll
    for (int cc = 0; cc < NCLS_; ++cc) {
        const float po = sigclip(logits[((size_t)(b * CH_ + cc * A_ + a)) * D_ * HW + sp]);
        float wo = fmaxf(po - (pt - 0.1f), 0.0f);
        wo = (po > 0.5f && ptg) ? wo : 0.0f;
        wo = zr[b][cc] ? 0.0f : wo;
        wo *= vf;
        loth -= __logf(1.0f - po) * wo;
        coth += wo;
    }

    // neg partials (grid is 1 block; stride over nb)
    float l = 0.0f, c = 0.0f;
    for (int i = tid; i < nb; i += 256) {
        l += partials[2 * (size_t)i];
        c += partials[2 * (size_t)i + 1];
    }

    #pragma unroll
    for (int off = 32; off > 0; off >>= 1) {
        lpos += __shfl_down(lpos, off);
        cpos += __shfl_down(cpos, off);
        loth += __shfl_down(loth, off);
        coth += __shfl_down(coth, off);
        l    += __shfl_down(l, off);
        c    += __shfl_down(c, off);
    }
    __shared__ float r6[4][6];
    const int lane = tid & 63, wv = tid >> 6;
    if (lane == 0) {
        r6[wv][0] = lpos; r6[wv][1] = cpos; r6[wv][2] = loth;
        r6[wv][3] = coth; r6[wv][4] = l;    r6[wv][5] = c;
    }
    __syncthreads();
    if (tid == 0) {
        out[0] = r6[0][0] + r6[1][0] + r6[2][0] + r6[3][0];  // sum l_pos
        out[3] = r6[0][1] + r6[1][1] + r6[2][1] + r6[3][1];  // sum c_pos
        out[2] = r6[0][2] + r6[1][2] + r6[2][2] + r6[3][2];  // sum l_oth
        out[5] = r6[0][3] + r6[1][3] + r6[2][3] + r6[3][3];  // sum c_oth
        out[1] = r6[0][4] + r6[1][4] + r6[2][4] + r6[3][4];  // loss_neg
        out[4] = r6[0][5] + r6[1][5] + r6[2][5] + r6[3][5];  // count_neg
    }
}

extern "C" void kernel_launch(void* const* d_in, const int* in_sizes, int n_in,
                              void* d_out, int out_size, void* d_ws, size_t ws_size,
                              hipStream_t stream)
{
    const float* logits = (const float*)d_in[0];
    const float* prob   = (const float*)d_in[1];
    const int*   coord  = (const int*)d_in[2];
    const float* wcls   = (const float*)d_in[3];
    float* out = (float*)d_out;

    const int nb = B_ * A_ * NCLS_ * (D_ / TD) * (H_ / THT);   // 1152 blocks
    float* partials = (float*)d_ws;          // nb * 2 floats

    neg_kernel<<<dim3(nb), dim3(256), 0, stream>>>(logits, prob, partials);
    pos_reduce_kernel<<<dim3(1), dim3(256), 0, stream>>>(logits, prob, coord, wcls,
                                                         partials, nb, out);
}

// Round 4
// 138.034 us; speedup vs baseline: 1.0127x; 1.0127x over previous
//
#include <hip/hip_runtime.h>
#include <cstdint>
#include <cstddef>

// Problem constants (from reference)
#define B_    2
#define A_    3
#define NCLS_ 3
#define CH_   9      // N_CLS * A
#define D_    64
#define H_    128
#define W_    128
#define M_    128
#define TD    8      // d-planes per block tile  (R13: 16 -> 8, grid x2)
#define EPS_      1e-4f
#define ONE_M_EPS 0.9999f
#define NLOG2E    -1.4426950408889634f   // -log2(e)
#define LN2_      0.6931471805599453f

__device__ __forceinline__ float4 fmax4(float4 a, float4 b) {
    return make_float4(fmaxf(a.x, b.x), fmaxf(a.y, b.y),
                       fmaxf(a.z, b.z), fmaxf(a.w, b.w));
}

// gfx950: __builtin_amdgcn_exp2f = v_exp_f32 (2^x), __builtin_amdgcn_logf =
// v_log_f32 (log2 x) — per __clang_hip_math.h.
__device__ __forceinline__ float exp2_fast(float x) { return __builtin_amdgcn_exp2f(x); }
__device__ __forceinline__ float log2_fast(float x) { return __builtin_amdgcn_logf(x); }

// ---------------------------------------------------------------------------
// Negative-term kernel — R11 structure + TLP saturation (R13).
// History: R9 (h-walk, 4 ld/out) 40.0 us; R10 (LDS+barriers) 64.5; R11
// (d-walk reg-ring, 3.6 ld/out, 52 VGPR) 42.6; R12 (2-row, +67% MLP, same
// traffic) 43.8. Per-wave MLP and +-20% traffic are all NEUTRAL => the
// remaining unvaried axis is CU-level TLP. All variants ran grid=1152 = 4.5
// blocks/CU (~18 waves/CU requested, 35% occupancy measured in R10). The
// 52-VGPR R11 kernel is the only structure under the 64-VGPR occupancy
// cliff (32 waves/CU cap); give it a grid that can use the cap:
//   TD 16 -> 8, grid 1152 -> 2304 = 9 blocks/CU -> 8 resident (32 waves/CU).
// Cost: prologue amortization worsens loads/output 3.56 -> 4.38 (+23%) —
// irrelevant at 11% HBM utilization if the latency-TLP theory is right.
// Everything else identical to R11: loop over d, separable 3x3x3 max,
// hwm register ring, partner-half __shfl(lane^32) for h-neighbors, single
// halo row load, replicate-clamp d/h borders, -inf w selects, no barriers,
// no LDS staging. Exact float max => (pooled == logits) bit-exact.
// Swizzle: 2304 = 8 XCD x 288 chunk (bijective); htile fastest, then
// dchunk (d-halo neighbors same XCD), then bc.
// ---------------------------------------------------------------------------
struct Raw { float4 c, e, pg; };

__global__ __launch_bounds__(256) void neg_kernel(
    const float* __restrict__ logits, const float* __restrict__ prob,
    float* __restrict__ partials)
{
    const int orig = blockIdx.x;
    const int swz  = (orig & 7) * 288 + (orig >> 3);   // chunked XCD swizzle
    const int tid  = threadIdx.x;
    const int lw   = tid & 31;            // w-segment index
    const int lane = tid & 63;
    const int hwi  = tid >> 5;            // 0..7: row within tile
    const int half = hwi & 1;             // 0 = lower row of wave, 1 = upper
    const float NEG = -INFINITY;

    // tile decode: htile fastest, then dchunk, then bc
    const int htile  = swz & 15;          // 0..15 -> 8 h-rows each
    const int dchunk = (swz >> 4) & 7;    // 0..7  -> 8 d-planes each
    const int bc     = swz >> 7;          // 0..17 channel index b*CH + c
    const int b = bc / CH_;
    const int a = (bc - b * CH_) % A_;    // negmask channel -> a = c % A
    const int d0 = dchunk * TD;
    const int r  = htile * 8 + hwi;       // this thread's h-row (fixed)
    const int er = half ? min(r + 1, H_ - 1) : max(r - 1, 0);  // halo row

    const size_t HW = (size_t)H_ * W_;
    const float* Cb = logits + (size_t)bc * D_ * HW + (size_t)r  * W_ + 4 * lw;
    const float* Eb = logits + (size_t)bc * D_ * HW + (size_t)er * W_ + 4 * lw;
    const float* Pb = prob + (size_t)(b * A_ + a) * D_ * HW + (size_t)r * W_ + 4 * lw;

    auto ldc = [&](int dq) -> float4 {
        const int dc = min(max(dq, 0), D_ - 1);   // d replicate-clamp
        return *(const float4*)(Cb + (size_t)dc * HW);
    };
    auto lde = [&](int dq) -> float4 {
        const int dc = min(max(dq, 0), D_ - 1);
        return *(const float4*)(Eb + (size_t)dc * HW);
    };
    auto ldpg = [&](int dq) -> float4 {
        const int dc = min(max(dq, 0), D_ - 1);
        return *(const float4*)(Pb + (size_t)dc * HW);
    };
    // partner row (other half of the wave, same w segment)
    auto shfl4 = [&](float4 v) -> float4 {
        const int p = lane ^ 32;
        return make_float4(__shfl(v.x, p, 64), __shfl(v.y, p, 64),
                           __shfl(v.z, p, 64), __shfl(v.w, p, 64));
    };
    // vertical (h-direction) 3-row max of one plane
    auto hv = [&](const Raw& rw) -> float4 {
        return fmax4(rw.c, fmax4(rw.e, shfl4(rw.c)));
    };

    // ---- prologue: planes d0-1 .. d0+2 in flight ----
    Raw rm1; rm1.c = ldc(d0 - 1); rm1.e = lde(d0 - 1);
    Raw r0;  r0.c  = ldc(d0);     r0.e  = lde(d0);     r0.pg  = ldpg(d0);
    Raw rawD; rawD.c = ldc(d0+1); rawD.e = lde(d0+1);  rawD.pg = ldpg(d0+1);
    Raw rawE; rawE.c = ldc(d0+2); rawE.e = lde(d0+2);  rawE.pg = ldpg(d0+2);

    float4 hwmA = hv(rm1);       // hwm[d0-1]
    float4 hwmB = hv(r0);        // hwm[d0]
    float4 xc   = r0.c;          // center values of output plane d0
    float4 pgc  = r0.pg;

    float lacc2 = 0.0f, cacc = 0.0f;   // lacc2 accumulates log2 units

    #pragma unroll
    for (int j = 0; j < TD; ++j) {
        // issue plane d0+j+3 (deepest) before touching anything in flight
        Raw rawN = rawE;
        if (j <= TD - 3) {
            rawN.c = ldc(d0 + j + 3); rawN.e = lde(d0 + j + 3);
            rawN.pg = ldpg(d0 + j + 3);
        }

        // combine plane d+1 (issued 2 iterations ago)
        const float4 hwmC = hv(rawD);      // hwm[d+1]
        const float4 xN   = rawD.c;
        const float4 pgN  = rawD.pg;

        // d-direction max for output plane d = d0+j
        float4 cm = fmax4(hwmA, fmax4(hwmB, hwmC));
        // w-direction neighbors across lanes (w borders: -inf select)
        const float lftv = __shfl(cm.w, (lane + 63) & 63, 64);
        const float rgtv = __shfl(cm.x, (lane + 1) & 63, 64);
        const float left  = (lw == 0)  ? NEG : lftv;
        const float right = (lw == 31) ? NEG : rgtv;
        float4 m;
        m.x = fmaxf(left, fmaxf(cm.x, cm.y));
        m.y = fmaxf(cm.x, fmaxf(cm.y, cm.z));
        m.z = fmaxf(cm.y, fmaxf(cm.z, cm.w));
        m.w = fmaxf(cm.z, fmaxf(cm.w, right));

        // epilogue: cheap pre-condition; wave-uniform skip of transcendentals
        {
            const float x = xc.x;
            const bool pre = (pgc.x == -1.0f) & (m.x == x);
            if (__any(pre)) {
                const float u = exp2_fast(x * NLOG2E);             // e^-x
                const float p = __builtin_amdgcn_fmed3f(
                                    __builtin_amdgcn_rcpf(1.0f + u), EPS_, ONE_M_EPS);
                const float wn = (pre & (p > EPS_)) ? p * p : 0.0f;
                cacc += wn;
                lacc2 = fmaf(log2_fast(1.0f - p), wn, lacc2);
            }
        }
        {
            const float x = xc.y;
            const bool pre = (pgc.y == -1.0f) & (m.y == x);
            if (__any(pre)) {
                const float u = exp2_fast(x * NLOG2E);
                const float p = __builtin_amdgcn_fmed3f(
                                    __builtin_amdgcn_rcpf(1.0f + u), EPS_, ONE_M_EPS);
                const float wn = (pre & (p > EPS_)) ? p * p : 0.0f;
                cacc += wn;
                lacc2 = fmaf(log2_fast(1.0f - p), wn, lacc2);
            }
        }
        {
            const float x = xc.z;
            const bool pre = (pgc.z == -1.0f) & (m.z == x);
            if (__any(pre)) {
                const float u = exp2_fast(x * NLOG2E);
                const float p = __builtin_amdgcn_fmed3f(
                                    __builtin_amdgcn_rcpf(1.0f + u), EPS_, ONE_M_EPS);
                const float wn = (pre & (p > EPS_)) ? p * p : 0.0f;
                cacc += wn;
                lacc2 = fmaf(log2_fast(1.0f - p), wn, lacc2);
            }
        }
        {
            const float x = xc.w;
            const bool pre = (pgc.w == -1.0f) & (m.w == x);
            if (__any(pre)) {
                const float u = exp2_fast(x * NLOG2E);
                const float p = __builtin_amdgcn_fmed3f(
                                    __builtin_amdgcn_rcpf(1.0f + u), EPS_, ONE_M_EPS);
                const float wn = (pre & (p > EPS_)) ? p * p : 0.0f;
                cacc += wn;
                lacc2 = fmaf(log2_fast(1.0f - p), wn, lacc2);
            }
        }

        // rotate rings
        hwmA = hwmB; hwmB = hwmC;
        xc = xN; pgc = pgN;
        rawD = rawE; rawE = rawN;
    }

    float lacc = lacc2 * (-LN2_);      // convert log2 -> -ln

    // block reduction: wave shuffle then cross-wave via LDS
    #pragma unroll
    for (int off = 32; off > 0; off >>= 1) {
        lacc += __shfl_down(lacc, off);
        cacc += __shfl_down(cacc, off);
    }
    __shared__ float rl[4], rc[4];
    const int wv = threadIdx.x >> 6;
    if (lane == 0) { rl[wv] = lacc; rc[wv] = cacc; }
    __syncthreads();
    if (threadIdx.x == 0) {
        partials[2 * (size_t)blockIdx.x]     = rl[0] + rl[1] + rl[2] + rl[3];
        partials[2 * (size_t)blockIdx.x + 1] = rc[0] + rc[1] + rc[2] + rc[3];
    }
}

// ---------------------------------------------------------------------------
// Fused positive/other terms + final reduction (single block).
// Output order: [sum l_pos, loss_neg, sum l_oth, sum c_pos, count_neg, sum c_oth]
// ---------------------------------------------------------------------------
__global__ __launch_bounds__(256) void pos_reduce_kernel(
    const float* __restrict__ logits, const float* __restrict__ prob,
    const int* __restrict__ coord, const float* __restrict__ wcls,
    const float* __restrict__ partials, int nb, float* __restrict__ out)
{
    const int tid = threadIdx.x;
    const int b = tid >> 7;               // 0 or 1
    const int m = tid & (M_ - 1);
    __shared__ int zr[B_][NCLS_];
    if (tid < B_ * NCLS_) zr[tid / NCLS_][tid % NCLS_] = 0;
    __syncthreads();

    const int* cg = coord + ((size_t)b * M_ + m) * 4;
    const int c0 = cg[0];
    const bool valid = c0 > -1;
    const int a = valid ? c0    : 0;
    const int d = valid ? cg[1] : 0;
    const int h = valid ? cg[2] : 0;
    const int w = valid ? cg[3] : 0;

    const size_t HW = (size_t)H_ * W_;
    const size_t sp = (size_t)d * HW + (size_t)h * W_ + w;

    const float pv = prob[((size_t)b * A_ + a) * D_ * HW + sp];
    const int cls = valid ? ((int)pv - 1) : 0;
    if (valid) zr[b][cls] = 1;            // zero_rows flags (benign race)
    __syncthreads();

    auto sigclip = [](float x) {
        float p = 1.0f / (1.0f + __expf(-x));
        return fminf(fmaxf(p, EPS_), ONE_M_EPS);
    };

    const float vf = valid ? 1.0f : 0.0f;
    const float pt = sigclip(logits[((size_t)(b * CH_ + cls * A_ + a)) * D_ * HW + sp]);
    const float wp = (1.0f - pt) * (1.0f - pt) * wcls[cls] * vf;
    float lpos = -__logf(pt) * wp;
    float cpos = wp;

    float loth = 0.0f, coth = 0.0f;
    const bool ptg = pt > 0.5f;
    #pragma unroll
    for (int cc = 0; cc < NCLS_; ++cc) {
        const float po = sigclip(logits[((size_t)(b * CH_ + cc * A_ + a)) * D_ * HW + sp]);
        float wo = fmaxf(po - (pt - 0.1f), 0.0f);
        wo = (po > 0.5f && ptg) ? wo : 0.0f;
        wo = zr[b][cc] ? 0.0f : wo;
        wo *= vf;
        loth -= __logf(1.0f - po) * wo;
        coth += wo;
    }

    // neg partials (grid is 1 block; stride over nb)
    float l = 0.0f, c = 0.0f;
    for (int i = tid; i < nb; i += 256) {
        l += partials[2 * (size_t)i];
        c += partials[2 * (size_t)i + 1];
    }

    #pragma unroll
    for (int off = 32; off > 0; off >>= 1) {
        lpos += __shfl_down(lpos, off);
        cpos += __shfl_down(cpos, off);
        loth += __shfl_down(loth, off);
        coth += __shfl_down(coth, off);
        l    += __shfl_down(l, off);
        c    += __shfl_down(c, off);
    }
    __shared__ float r6[4][6];
    const int lane = tid & 63, wv = tid >> 6;
    if (lane == 0) {
        r6[wv][0] = lpos; r6[wv][1] = cpos; r6[wv][2] = loth;
        r6[wv][3] = coth; r6[wv][4] = l;    r6[wv][5] = c;
    }
    __syncthreads();
    if (tid == 0) {
        out[0] = r6[0][0] + r6[1][0] + r6[2][0] + r6[3][0];  // sum l_pos
        out[3] = r6[0][1] + r6[1][1] + r6[2][1] + r6[3][1];  // sum c_pos
        out[2] = r6[0][2] + r6[1][2] + r6[2][2] + r6[3][2];  // sum l_oth
        out[5] = r6[0][3] + r6[1][3] + r6[2][3] + r6[3][3];  // sum c_oth
        out[1] = r6[0][4] + r6[1][4] + r6[2][4] + r6[3][4];  // loss_neg
        out[4] = r6[0][5] + r6[1][5] + r6[2][5] + r6[3][5];  // count_neg
    }
}

extern "C" void kernel_launch(void* const* d_in, const int* in_sizes, int n_in,
                              void* d_out, int out_size, void* d_ws, size_t ws_size,
                              hipStream_t stream)
{
    const float* logits = (const float*)d_in[0];
    const float* prob   = (const float*)d_in[1];
    const int*   coord  = (const int*)d_in[2];
    const float* wcls   = (const float*)d_in[3];
    float* out = (float*)d_out;

    const int nb = B_ * CH_ * (H_ / 8) * (D_ / TD);    // 2304 blocks, exact
    float* partials = (float*)d_ws;          // nb * 2 floats

    neg_kernel<<<dim3(nb), dim3(256), 0, stream>>>(logits, prob, partials);
    pos_reduce_kernel<<<dim3(1), dim3(256), 0, stream>>>(logits, prob, coord, wcls,
                                                         partials, nb, out);
}